// Round 4
// baseline (507.515 us; speedup 1.0000x reference)
//
#include <hip/hip_runtime.h>

// MeanSpikeClassifier: interval-graph connected components.
// N = 96*96 = 9216 pixels, T = 64 steps, out = masks[N,N] ++ mean_grid[N] (f32).
//
// adj(i,j) = (1 - |v_i - v_j| >= 0.6) is an interval graph on the value line.
// Components = maximal value-runs not split by a "gap" (a value with no
// adjacent value above it). component_id(i) = #gap-start values < v_i.
// labels[i] = min pixel index in component (== reference while_loop fixpoint).
// masks is ultra-sparse: exactly N ones (pixel n lights row labels[n]).
//
// R3 accounting: the ~215us fills (WRITE_SIZE = 4 x full output exactly) are
// HARNESS POISON passes, and they come in PAIRS per iteration (~430us
// in-window, untouchable). Our own write pass is ~53us. This round: simplest
// possible zero-writer (grid-stride, regular dwordx4 stores, no loads) +
// 36KB scatter, to discriminate "nt-store slowness" vs "poison floor".
// (R4 = R3 resubmitted verbatim; R3 run died to a container-broker failure.)

#define N_PIX 9216

typedef float f32x4 __attribute__((ext_vector_type(4)));

// K0: stream zeros over the N*N mask region. Fill-shaped: grid-stride,
// 2048 blocks x 256 threads, one dwordx4 regular store per iter, no loads.
__global__ void __launch_bounds__(256) k_zero(f32x4* __restrict__ out4) {
    const size_t nchunks = (size_t)N_PIX * N_PIX / 4;   // 21,233,664
    const f32x4 z = {0.f, 0.f, 0.f, 0.f};
    size_t stride = (size_t)gridDim.x * blockDim.x;
    for (size_t i = (size_t)blockIdx.x * blockDim.x + threadIdx.x; i < nchunks; i += stride)
        out4[i] = z;
}

// K1: per-pixel mean of late steps; also init compmin/ngaps (ws is re-poisoned
// to 0xAA before every timed launch, so init must happen every call).
__global__ void k_means(const float* __restrict__ spike, const int* __restrict__ cs_p,
                        int T, float* __restrict__ v, float* __restrict__ out_grid,
                        int* __restrict__ compmin, int* __restrict__ ngaps) {
    int n = blockIdx.x * blockDim.x + threadIdx.x;
    if (n >= N_PIX) return;
    int cs = cs_p[0];
    int start = cs - 1;
    if (start < 0) start = 0;
    if (start > T - 1) start = T - 1;
    float s = 0.0f;
    for (int t = start; t < T; ++t)       // coalesced across n for each t
        s += spike[(size_t)t * N_PIX + n];
    float val = s / (float)(T - start);
    v[n] = val;
    out_grid[n] = val;
    compmin[n] = 0x7fffffff;
    if (n == 0) *ngaps = 0;
}

// K2: one block per pixel k — is k a "gap start"?
// gap(k) := (exists v_j > v_k) && (no j with v_j > v_k && 1-(v_j-v_k) >= 0.6f)
// Exact float predicate of the reference (monotone in the diff).
__global__ void __launch_bounds__(256) k_gaps(const float* __restrict__ v,
                                              float* __restrict__ gaps,
                                              int* __restrict__ ngaps) {
    int k = blockIdx.x;
    float vk = v[k];
    int hasG = 0, hasAdj = 0;
    for (int j = threadIdx.x; j < N_PIX; j += 256) {
        float vj = v[j];                   // 36 KB array, L1/L2-resident
        if (vj > vk) {
            hasG = 1;
            if (1.0f - (vj - vk) >= 0.6f) hasAdj = 1;
        }
    }
    __shared__ int sG, sA;
    if (threadIdx.x == 0) { sG = 0; sA = 0; }
    __syncthreads();
    if (hasG)   atomicOr(&sG, 1);
    if (hasAdj) atomicOr(&sA, 1);
    __syncthreads();
    if (threadIdx.x == 0 && sG && !sA) {
        int idx = atomicAdd(ngaps, 1);     // order-independent downstream
        gaps[idx] = vk;
    }
}

// K3: component id = #gap values strictly below v_i; per-component min index.
__global__ void k_ids(const float* __restrict__ v, const float* __restrict__ gaps,
                      const int* __restrict__ ngaps, int* __restrict__ gid,
                      int* __restrict__ compmin) {
    int i = blockIdx.x * blockDim.x + threadIdx.x;
    if (i >= N_PIX) return;
    float vi = v[i];
    int ng = *ngaps;                       // ~0-2 for this data
    int g = 0;
    for (int t = 0; t < ng; ++t) g += (gaps[t] < vi) ? 1 : 0;
    gid[i] = g;
    atomicMin(&compmin[g], i);
}

// K4: scatter the N ones into the zeroed mask: out[compmin[gid[n]]*N + n] = 1.
// (36 KB of scattered dword stores; for this data all labels are 0 ->
// fully coalesced row-0 write.)
__global__ void k_scatter(const int* __restrict__ gid, const int* __restrict__ compmin,
                          float* __restrict__ out) {
    int n = blockIdx.x * blockDim.x + threadIdx.x;
    if (n >= N_PIX) return;
    int label = compmin[gid[n]];
    out[(size_t)label * N_PIX + n] = 1.0f;
}

extern "C" void kernel_launch(void* const* d_in, const int* in_sizes, int n_in,
                              void* d_out, int out_size, void* d_ws, size_t ws_size,
                              hipStream_t stream) {
    const float* spike = (const float*)d_in[0];
    const int* cs = (const int*)d_in[1];
    int T = in_sizes[0] / N_PIX;           // 64

    float* out = (float*)d_out;
    float* out_grid = out + (size_t)N_PIX * N_PIX;

    // workspace layout (~150 KB)
    float* v       = (float*)d_ws;
    float* gaps    = v + N_PIX;
    int*   ngaps   = (int*)(gaps + N_PIX);
    int*   gid     = ngaps + 4;
    int*   compmin = gid + N_PIX;

    k_zero   <<<2048, 256, 0, stream>>>((f32x4*)out);
    k_means  <<<(N_PIX + 255) / 256, 256, 0, stream>>>(spike, cs, T, v, out_grid,
                                                       compmin, ngaps);
    k_gaps   <<<N_PIX, 256, 0, stream>>>(v, gaps, ngaps);
    k_ids    <<<(N_PIX + 255) / 256, 256, 0, stream>>>(v, gaps, ngaps, gid, compmin);
    k_scatter<<<(N_PIX + 255) / 256, 256, 0, stream>>>(gid, compmin, out);
}